// Round 5
// baseline (5582.650 us; speedup 1.0000x reference)
//
#include <hip/hip_runtime.h>

typedef unsigned short u16;
typedef __attribute__((ext_vector_type(8))) __bf16 bf16x8;
typedef __attribute__((ext_vector_type(4))) float floatx4;
typedef __attribute__((ext_vector_type(16))) float floatx16;

#define NTOK 1296      // P + H*(NO+NA) = 16 + 32*40
#define BN_TOT 10368   // B * NTOK
#define DMODEL 768
#define DFF 3072
#define NHEAD 12
#define DHEAD 64
#define NLAYER 12
#define NQT2 11        // ceil(NTOK/128)
#define SCALE_QK 0.125f  // 1/sqrt(64)

__device__ __forceinline__ u16 f2bf(float f) {
    unsigned u = __builtin_bit_cast(unsigned, f);
    unsigned r = (u + 0x7FFFu + ((u >> 16) & 1u)) >> 16;
    return (u16)r;
}

__device__ __forceinline__ unsigned cvt_pk_bf16(float lo, float hi) {
    unsigned r;
    asm("v_cvt_pk_bf16_f32 %0, %1, %2" : "=v"(r) : "v"(lo), "v"(hi));
    return r;
}

__device__ __forceinline__ float gelu_f(float x) {
    float u = 0.7978845608028654f * (x + 0.044715f * x * x * x);
    float t = 1.f - 2.f / (__expf(2.f * u) + 1.f);   // tanh(u)
    return 0.5f * x * (1.f + t);
}

// ---------------- input assembly ----------------
__global__ void assemble_x(const float* __restrict__ prefix,
                           const float* __restrict__ obs,
                           const float* __restrict__ act,
                           float* __restrict__ X) {
    int idx = blockIdx.x * 256 + threadIdx.x;
    if (idx >= BN_TOT * DMODEL) return;
    int d = idx % DMODEL;
    int n = (idx / DMODEL) % NTOK;
    int b = idx / (DMODEL * NTOK);
    float v;
    if (n < 16) {
        v = prefix[((size_t)b * 16 + n) * DMODEL + d];
    } else {
        int q = n - 16;
        int m = q / 40, r = q % 40;
        if (r < 32) v = obs[(((size_t)b * 32 + m) * 32 + r) * DMODEL + d];
        else        v = act[(((size_t)b * 32 + m) * 8 + (r - 32)) * DMODEL + d];
    }
    X[idx] = v;
}

__global__ void build_pad(const int* __restrict__ pm,
                          const int* __restrict__ om,
                          const int* __restrict__ am,
                          unsigned char* __restrict__ pad) {
    int idx = blockIdx.x * 256 + threadIdx.x;
    if (idx >= BN_TOT) return;
    int n = idx % NTOK, b = idx / NTOK;
    int v;
    if (n < 16) v = pm[b * 16 + n];
    else {
        int q = n - 16;
        int m = q / 40, r = q % 40;
        v = (r < 32) ? om[(b * 32 + m) * 32 + r] : am[(b * 32 + m) * 8 + (r - 32)];
    }
    pad[idx] = (v != 0) ? 1 : 0;
}

__global__ void build_biascat(const float* __restrict__ bq,
                              const float* __restrict__ bk,
                              const float* __restrict__ bv,
                              float* __restrict__ bc) {
    int idx = blockIdx.x * 256 + threadIdx.x;
    if (idx >= NLAYER * 2304) return;
    int l = idx / 2304, c = idx % 2304;
    int which = c / 768, cc = c % 768;
    const float* src = (which == 0) ? bq : (which == 1) ? bk : bv;
    bc[idx] = src[l * 768 + cc];
}

// ---------------- weight transpose + cvt: W fp32 [K][Nc] -> bf16 [Nc][K] ----------------
__global__ void transpose_cvt(const float* __restrict__ src, u16* __restrict__ dst,
                              int K, int Nc, long layerStride) {
    src += (size_t)blockIdx.z * K * Nc;
    dst += (size_t)blockIdx.z * layerStride;
    __shared__ float tile[32][33];
    int n0 = blockIdx.x * 32, k0 = blockIdx.y * 32;
    int tx = threadIdx.x, ty = threadIdx.y;
#pragma unroll
    for (int i = 0; i < 4; ++i)
        tile[ty + i * 8][tx] = src[(size_t)(k0 + ty + i * 8) * Nc + n0 + tx];
    __syncthreads();
#pragma unroll
    for (int i = 0; i < 4; ++i) {
        int n = n0 + ty + i * 8;
        dst[(size_t)n * K + k0 + tx] = f2bf(tile[tx][ty + i * 8]);
    }
}

// ---------------- LayerNorm: one wave per row, no barriers ----------------
__global__ __launch_bounds__(256) void ln_kernel(const float* __restrict__ x,
                                                 const float* __restrict__ s,
                                                 const float* __restrict__ bb,
                                                 u16* __restrict__ obf,
                                                 float* __restrict__ of32) {
    int row = blockIdx.x * 4 + (threadIdx.x >> 6);
    int lane = threadIdx.x & 63;
    const float4* xv = (const float4*)(x + (size_t)row * DMODEL);
    float4 v[3];
    v[0] = xv[lane]; v[1] = xv[lane + 64]; v[2] = xv[lane + 128];
    float sum = 0.f, sq = 0.f;
#pragma unroll
    for (int i = 0; i < 3; ++i) {
        sum += v[i].x + v[i].y + v[i].z + v[i].w;
        sq  += v[i].x * v[i].x + v[i].y * v[i].y + v[i].z * v[i].z + v[i].w * v[i].w;
    }
#pragma unroll
    for (int d = 32; d > 0; d >>= 1) {
        sum += __shfl_xor(sum, d);
        sq  += __shfl_xor(sq, d);
    }
    float mu = sum * (1.f / DMODEL);
    float var = sq * (1.f / DMODEL) - mu * mu;
    float rstd = rsqrtf(var + 1e-6f);
    const float4* sv = (const float4*)s;
    const float4* bv = (const float4*)bb;
#pragma unroll
    for (int i = 0; i < 3; ++i) {
        float4 sc = sv[lane + i * 64], bc = bv[lane + i * 64];
        float y0 = (v[i].x - mu) * rstd * sc.x + bc.x;
        float y1 = (v[i].y - mu) * rstd * sc.y + bc.y;
        float y2 = (v[i].z - mu) * rstd * sc.z + bc.z;
        float y3 = (v[i].w - mu) * rstd * sc.w + bc.w;
        size_t base = (size_t)row * DMODEL + i * 256 + lane * 4;
        if (obf) {
            uint2 pk;
            pk.x = (unsigned)f2bf(y0) | ((unsigned)f2bf(y1) << 16);
            pk.y = (unsigned)f2bf(y2) | ((unsigned)f2bf(y3) << 16);
            *(uint2*)&obf[base] = pk;
        } else {
            float4 o = {y0, y1, y2, y3};
            *(float4*)&of32[base] = o;
        }
    }
}

// ---------------- GEMM: 2-phase double-buffered global_load_lds staging ----------------
template <int EPI>
__global__ __launch_bounds__(256) void gemm_k(const u16* __restrict__ A,
                                              const u16* __restrict__ Bt,
                                              const float* __restrict__ bias,
                                              const float* __restrict__ resid,
                                              void* __restrict__ outp,
                                              int M, int Nc, int K) {
    __shared__ __attribute__((aligned(16))) u16 As[2][4096];  // 512 slots x 16B
    __shared__ __attribute__((aligned(16))) u16 Bs[2][4096];
    int tid = threadIdx.x;
    int bc = blockIdx.x, br = blockIdx.y;
    int lane = tid & 63, w = tid >> 6;
    int wr = (w >> 1) * 64, wc = (w & 1) * 64;
    int lr = lane & 15, C = lane >> 4;
    floatx4 acc[4][4] = {};

    int r0 = tid >> 2;       // staging row within 64-row half (0..63)
    int cph = tid & 3;       // physical 16B chunk slot within row
    const u16* Abase = A + (size_t)(br * 128) * K;
    const u16* Bbase = Bt + (size_t)(bc * 128) * K;

    auto stageg = [&](int buf, int k0) {
#pragma unroll
        for (int i = 0; i < 2; ++i) {
            int r = i * 64 + r0;
            int cl = cph ^ ((r >> 1) & 3);
            const u16* ga = Abase + (size_t)r * K + k0 + cl * 8;
            const u16* gb = Bbase + (size_t)r * K + k0 + cl * 8;
            __builtin_amdgcn_global_load_lds(
                (const __attribute__((address_space(1))) void*)ga,
                (__attribute__((address_space(3))) void*)&As[buf][(i * 256 + w * 64) * 8], 16, 0, 0);
            __builtin_amdgcn_global_load_lds(
                (const __attribute__((address_space(1))) void*)gb,
                (__attribute__((address_space(3))) void*)&Bs[buf][(i * 256 + w * 64) * 8], 16, 0, 0);
        }
    };

    stageg(0, 0);
    __syncthreads();
    int cur = 0;

    for (int k0 = 0; k0 < K; k0 += 32) {
        if (k0 + 32 < K) stageg(cur ^ 1, k0 + 32);   // prefetch next K-slice
        bf16x8 af[4], bf[4];
#pragma unroll
        for (int i = 0; i < 4; ++i) {
            int R = wr + i * 16 + lr;
            af[i] = *(const bf16x8*)&As[cur][(R * 4 + (C ^ ((R >> 1) & 3))) * 8];
        }
#pragma unroll
        for (int i = 0; i < 4; ++i) {
            int R = wc + i * 16 + lr;
            bf[i] = *(const bf16x8*)&Bs[cur][(R * 4 + (C ^ ((R >> 1) & 3))) * 8];
        }
        __builtin_amdgcn_s_setprio(1);
#pragma unroll
        for (int i = 0; i < 4; ++i)
#pragma unroll
            for (int j = 0; j < 4; ++j)
                acc[i][j] = __builtin_amdgcn_mfma_f32_16x16x32_bf16(af[i], bf[j], acc[i][j], 0, 0, 0);
        __builtin_amdgcn_s_setprio(0);
        __syncthreads();             // drains prefetch; all warps done with cur
        cur ^= 1;
    }

    int gr0 = br * 128 + wr, gc0 = bc * 128 + wc;
#pragma unroll
    for (int i = 0; i < 4; ++i) {
#pragma unroll
        for (int j = 0; j < 4; ++j) {
#pragma unroll
            for (int r = 0; r < 4; ++r) {
                int grow = gr0 + i * 16 + (lane >> 4) * 4 + r;
                int gcol = gc0 + j * 16 + lr;
                float v = acc[i][j][r] + bias[gcol];
                if constexpr (EPI == 2) {
                    ((u16*)outp)[(size_t)grow * Nc + gcol] = f2bf(gelu_f(v));
                } else if constexpr (EPI == 3) {
                    size_t idx = (size_t)grow * Nc + gcol;
                    ((float*)outp)[idx] = resid[idx] + v;
                } else {  // EPI == 4: fused QKV epilogue; outp = Qb (K,V at fixed offsets)
                    int b = grow / NTOK, n = grow % NTOK;
                    int which = gcol / 768;
                    int c = gcol - which * 768;
                    int nh = c >> 6, dh = c & 63;
                    u16* base = (u16*)outp + (size_t)which * ((size_t)BN_TOT * DMODEL);
                    if (which < 2)
                        base[(((size_t)b * NHEAD + nh) * NTOK + n) * DHEAD + dh] = f2bf(v);
                    else
                        base[(((size_t)b * NHEAD + nh) * DHEAD + dh) * NTOK + n] = f2bf(v);
                }
            }
        }
    }
}

// ---------------- fused attention: 32x32x16 MFMA, 32 q/warp (128 q/block),
// block-cooperative double-buffered K/V staging, per-lane softmax (1 shfl),
// swizzled per-warp P-LDS, setprio, XCD-grouped + longest-first ----------------
__global__ __launch_bounds__(256) void attn_k(const u16* __restrict__ Q,
                                              const u16* __restrict__ Kb,
                                              const u16* __restrict__ Vt,
                                              const unsigned char* __restrict__ pad,
                                              u16* __restrict__ O) {
    // K/V tiles 64x64 bf16, chunk(16B)-XOR swizzle: physical chunk cp of row r
    // holds logical chunk cp^(r&7)  (involution on staging-src and read)
    __shared__ __attribute__((aligned(16))) u16 Ks[2][64 * 64];
    __shared__ __attribute__((aligned(16))) u16 Vs[2][64 * 64];
    __shared__ __attribute__((aligned(16))) u16 plds[4][32 * 64];  // per warp: 32 q x 64 keys

    int wgid = blockIdx.x;
    int xcd = wgid & 7, slot = wgid >> 3;
    int qt = NQT2 - 1 - (slot % NQT2);        // longest q-tiles dispatch first
    int g = (slot / NQT2) * 8 + xcd;          // all tiles of (b,h) on one XCD
    int b = g / NHEAD, h = g % NHEAD;

    int tid = threadIdx.x, lane = tid & 63, w = tid >> 6;
    int ql = lane & 31, half = lane >> 5;
    int q0 = qt * 128 + w * 32;
    size_t bh = (size_t)(b * NHEAD + h);

    int lastrow = min(qt * 128 + 127, NTOK - 1);
    int jend = (lastrow < 16) ? 16 : 16 + 40 * ((lastrow - 16) / 40 + 1);
    jend = min(jend, NTOK);
    int njt = (jend + 63) >> 6;

    int q = q0 + ql;                 // this lane's query row (col of S^T / O^T)
    bool qok = q < NTOK;
    int tmax_obs = -1, tmax_act = -1;
    if (qok && q >= 16) {
        int qi = q - 16;
        int ti = qi / 40;
        bool gact = (qi % 40) >= 32;
        tmax_obs = ti;
        tmax_act = gact ? ti : -1;
    }

    // Q fragments (B operand of 32x32x16: col=q, k = 8*half + j within each
    // 16-wide d-slice), 1/sqrt(DH) pre-folded (exact *2^-3)
    bf16x8 qf[4];
    {
        const u16* qb = Q + (bh * NTOK + min(q, NTOK - 1)) * DHEAD + 8 * half;
#pragma unroll
        for (int m = 0; m < 4; ++m) {
            bf16x8 t = *(const bf16x8*)(qb + 16 * m);
#pragma unroll
            for (int i = 0; i < 8; ++i) qf[m][i] = (__bf16)((float)t[i] * SCALE_QK);
        }
    }

    // cooperative staging: 512 chunks x 16B per matrix; dest linear,
    // source pre-swizzled (involution both sides)
    auto stage = [&](int buf, int jt) {
#pragma unroll
        for (int i = 0; i < 2; ++i) {
            int r = i * 32 + (tid >> 3);             // tile row 0..63
            int cl = (tid & 7) ^ (r & 7);            // logical chunk fetched
            const u16* gk = Kb + (bh * NTOK + min(jt * 64 + r, NTOK - 1)) * DHEAD + cl * 8;
            const u16* gv = Vt + (bh * DHEAD + r) * NTOK + jt * 64 + cl * 8;
            __builtin_amdgcn_global_load_lds(
                (const __attribute__((address_space(1))) void*)gk,
                (__attribute__((address_space(3))) void*)&Ks[buf][(i * 256 + w * 64) * 8], 16, 0, 0);
            __builtin_amdgcn_global_load_lds(
                (const __attribute__((address_space(1))) void*)gv,
                (__attribute__((address_space(3))) void*)&Vs[buf][(i * 256 + w * 64) * 8], 16, 0, 0);
        }
    };

    floatx16 oacc[2] = {};           // oacc[dt][r]: O^T[d=32dt+(r&3)+8(r>>2)+4half][q]
    float mi = -3.0e38f, li = 0.f;   // per-lane (per-q) softmax state
    const unsigned char* padb = pad + (size_t)b * NTOK;

    stage(0, 0);
    __syncthreads();
    int cur = 0;

    for (int jt = 0; jt < njt; ++jt) {
        int j0 = jt * 64;
        if (jt + 1 < njt) stage(cur ^ 1, jt + 1);   // prefetch next tile

        // QK^T: S^T[key][q], two 32-key tiles; A=K (row=key, k=d), B=Q
        floatx16 s[2];
        __builtin_amdgcn_s_setprio(1);
#pragma unroll
        for (int kt = 0; kt < 2; ++kt) {
            int kk = kt * 32 + ql;
            floatx16 sa = {};
#pragma unroll
            for (int m = 0; m < 4; ++m) {
                bf16x8 kf = *(const bf16x8*)&Ks[cur][kk * 64 + (((2 * m + half) ^ (kk & 7)) << 3)];
                sa = __builtin_amdgcn_mfma_f32_32x32x16_bf16(kf, qf[m], sa, 0, 0, 0);
            }
            s[kt] = sa;
        }
        __builtin_amdgcn_s_setprio(0);

        // mask: reg r of tile kt holds key = j0 + 32kt + (r&3)+8(r>>2)+4half
        // -> per (kt,g=r>>2): 4 consecutive keys at kb0 = j0+32kt+8g+4half
#pragma unroll
        for (int kt = 0; kt < 2; ++kt) {
#pragma unroll
            for (int gg = 0; gg < 4; ++gg) {
                int kb0 = j0 + kt * 32 + 8 * gg + 4 * half;
                unsigned pw = (kb0 < NTOK) ? *(const unsigned*)(padb + kb0) : 0u;
                bool jpre = kb0 < 16;
                int tj0 = 0, rem0 = 0;
                if (!jpre) { int qj = kb0 - 16; tj0 = qj / 40; rem0 = qj - 40 * tj0; }
#pragma unroll
                for (int rr = 0; rr < 4; ++rr) {
                    int key = kb0 + rr;
                    bool colok = qok && (key < jend) && (((pw >> (8 * rr)) & 0xFFu) != 0);
                    bool ok;
                    if (jpre) ok = colok;
                    else {
                        int rem = rem0 + rr;
                        int tj = tj0 + (rem >= 40 ? 1 : 0);
                        int remr = rem >= 40 ? rem - 40 : rem;
                        int tm = (remr >= 32) ? tmax_act : tmax_obs;
                        ok = colok && (tj <= tm);
                    }
                    s[kt][4 * gg + rr] = ok ? s[kt][4 * gg + rr] : -1.0e9f;
                }
            }
        }

        // per-lane softmax over 32 scores + one cross-half butterfly
        float mt = s[0][0];
#pragma unroll
        for (int r = 1; r < 16; ++r) mt = fmaxf(mt, s[0][r]);
#pragma unroll
        for (int r = 0; r < 16; ++r) mt = fmaxf(mt, s[1][r]);
        mt = fmaxf(mt, __shfl_xor(mt, 32));
        float mnew = fmaxf(mi, mt);
        float alpha = __expf(mi - mnew);
        float rs = 0.f;
#pragma unroll
        for (int kt = 0; kt < 2; ++kt)
#pragma unroll
            for (int r = 0; r < 16; ++r) {
                float p = __expf(s[kt][r] - mnew);
                s[kt][r] = p;
                rs += p;
            }
        rs += __shfl_xor(rs, 32);
        li = li * alpha + rs;
        mi = mnew;
#pragma unroll
        for (int dt = 0; dt < 2; ++dt)
#pragma unroll
            for (int r = 0; r < 16; ++r) oacc[dt][r] *= alpha;

        // pack P row q into per-warp swizzled LDS: 8 chunks of 4 keys -> 8B each
#pragma unroll
        for (int kt = 0; kt < 2; ++kt)
#pragma unroll
            for (int gg = 0; gg < 4; ++gg) {
                uint2 pk;
                pk.x = cvt_pk_bf16(s[kt][4 * gg], s[kt][4 * gg + 1]);
                pk.y = cvt_pk_bf16(s[kt][4 * gg + 2], s[kt][4 * gg + 3]);
                int c = kt * 4 + gg;
                *(uint2*)&plds[w][ql * 64 + ((c ^ (ql & 7)) << 3) + 4 * half] = pk;
            }

        // PV: O^T += V^T(A) x P^T(B); 4 key-slices x 2 d-tiles
        __builtin_amdgcn_s_setprio(1);
#pragma unroll
        for (int ks = 0; ks < 4; ++ks) {
            bf16x8 pf = *(const bf16x8*)&plds[w][ql * 64 + (((2 * ks + half) ^ (ql & 7)) << 3)];
#pragma unroll
            for (int dt = 0; dt < 2; ++dt) {
                int dd = dt * 32 + ql;
                bf16x8 vf = *(const bf16x8*)&Vs[cur][dd * 64 + (((2 * ks + half) ^ (dd & 7)) << 3)];
                oacc[dt] = __builtin_amdgcn_mfma_f32_32x32x16_bf16(vf, pf, oacc[dt], 0, 0, 0);
            }
        }
        __builtin_amdgcn_s_setprio(0);

        __syncthreads();             // drains prefetch; all warps done with cur
        cur ^= 1;
    }

    // epilogue: lane holds O[q][d = 32dt+8g+4half+rr]; 4 contiguous d -> 8B stores
    if (q < NTOK) {
        float inv = 1.f / li;
#pragma unroll
        for (int dt = 0; dt < 2; ++dt)
#pragma unroll
            for (int gg = 0; gg < 4; ++gg) {
                uint2 pk;
                pk.x = cvt_pk_bf16(oacc[dt][4 * gg] * inv, oacc[dt][4 * gg + 1] * inv);
                pk.y = cvt_pk_bf16(oacc[dt][4 * gg + 2] * inv, oacc[dt][4 * gg + 3] * inv);
                int dbase = dt * 32 + 8 * gg + 4 * half;
                *(uint2*)&O[((size_t)b * NTOK + q) * DMODEL + h * DHEAD + dbase] = pk;
            }
    }
}

// ---------------- launcher ----------------
extern "C" void kernel_launch(void* const* d_in, const int* in_sizes, int n_in,
                              void* d_out, int out_size, void* d_ws, size_t ws_size,
                              hipStream_t stream) {
    const float* prefix = (const float*)d_in[0];
    const float* obs    = (const float*)d_in[1];
    const float* act    = (const float*)d_in[2];
    const float* ln1_s  = (const float*)d_in[3];
    const float* ln1_b  = (const float*)d_in[4];
    const float* ln2_s  = (const float*)d_in[5];
    const float* ln2_b  = (const float*)d_in[6];
    const float* wq = (const float*)d_in[7];
    const float* wk = (const float*)d_in[8];
    const float* wv = (const float*)d_in[9];
    const float* wo = (const float*)d_in[10];
    const float* bq = (const float*)d_in[11];
    const float* bk = (const float*)d_in[12];
    const float* bv = (const float*)d_in[13];
    const float* bo = (const float*)d_in[14];
    const float* w1 = (const float*)d_in[15];
    const float* b1 = (const float*)d_in[16];
    const float* w2 = (const float*)d_in[17];
    const float* b2 = (const float*)d_in[18];
    const float* lnf_s = (const float*)d_in[19];
    const float* lnf_b = (const float*)d_in[20];
    const int* pm = (const int*)d_in[21];
    const int* om = (const int*)d_in[22];
    const int* am = (const int*)d_in[23];
    float* out = (float*)d_out;

    char* ws = (char*)d_ws;
    size_t off = 0;
    auto carve = [&](size_t bytes) -> char* {
        char* p = ws + off;
        off += (bytes + 255) & ~(size_t)255;
        return p;
    };
    float* X   = (float*)carve((size_t)BN_TOT * DMODEL * 4);
    u16*   Hb  = (u16*)carve((size_t)BN_TOT * DMODEL * 2);
    u16*   QKV = (u16*)carve((size_t)3 * BN_TOT * DMODEL * 2);  // Q | K | V^T contiguous
    u16*   Qb  = QKV;
    u16*   Kbf = QKV + (size_t)BN_TOT * DMODEL;
    u16*   Vt  = QKV + (size_t)2 * BN_TOT * DMODEL;
    u16*   Ob  = (u16*)carve((size_t)BN_TOT * DMODEL * 2);
    u16*   MID = (u16*)carve((size_t)BN_TOT * DFF * 2);
    unsigned char* PAD = (unsigned char*)carve(BN_TOT);
    float* BIASC = (float*)carve((size_t)NLAYER * 2304 * 4);
    u16*   WT  = (u16*)carve((size_t)NLAYER * 7077888 * 2);
    if (off > ws_size) return;

    const long LSTR = 7077888;
    const long OWQ = 0, OWO = 1769472, OW1 = 2359296, OW2 = 4718592;
    const long OWK = 589824, OWV = 1179648;

    dim3 blk(256);
    assemble_x<<<(BN_TOT * DMODEL + 255) / 256, blk, 0, stream>>>(prefix, obs, act, X);
    build_pad<<<(BN_TOT + 255) / 256, blk, 0, stream>>>(pm, om, am, PAD);
    build_biascat<<<(NLAYER * 2304 + 255) / 256, blk, 0, stream>>>(bq, bk, bv, BIASC);

    dim3 tb(32, 8);
    transpose_cvt<<<dim3(DMODEL / 32, DMODEL / 32, NLAYER), tb, 0, stream>>>(wq, WT + OWQ, DMODEL, DMODEL, LSTR);
    transpose_cvt<<<dim3(DMODEL / 32, DMODEL / 32, NLAYER), tb, 0, stream>>>(wk, WT + OWK, DMODEL, DMODEL, LSTR);
    transpose_cvt<<<dim3(DMODEL / 32, DMODEL / 32, NLAYER), tb, 0, stream>>>(wv, WT + OWV, DMODEL, DMODEL, LSTR);
    transpose_cvt<<<dim3(DMODEL / 32, DMODEL / 32, NLAYER), tb, 0, stream>>>(wo, WT + OWO, DMODEL, DMODEL, LSTR);
    transpose_cvt<<<dim3(DFF / 32, DMODEL / 32, NLAYER), tb, 0, stream>>>(w1, WT + OW1, DMODEL, DFF, LSTR);
    transpose_cvt<<<dim3(DMODEL / 32, DFF / 32, NLAYER), tb, 0, stream>>>(w2, WT + OW2, DFF, DMODEL, LSTR);

    dim3 g6(DMODEL / 128, BN_TOT / 128);
    dim3 gqkv(2304 / 128, BN_TOT / 128);
    dim3 g24(DFF / 128, BN_TOT / 128);
    dim3 ga(NQT2 * NHEAD * 8);   // 1056, XCD-grouped decode inside kernel
    dim3 gln(BN_TOT / 4);

    for (int l = 0; l < NLAYER; ++l) {
        const u16* WTl = WT + (size_t)l * LSTR;
        ln_kernel<<<gln, blk, 0, stream>>>(X, ln1_s + l * DMODEL, ln1_b + l * DMODEL, Hb, nullptr);
        gemm_k<4><<<gqkv, blk, 0, stream>>>(Hb, WTl + OWQ, BIASC + l * 2304, nullptr, Qb, BN_TOT, 2304, DMODEL);
        attn_k<<<ga, blk, 0, stream>>>(Qb, Kbf, Vt, PAD, Ob);
        gemm_k<3><<<g6, blk, 0, stream>>>(Ob, WTl + OWO, bo + l * DMODEL, X, X, BN_TOT, DMODEL, DMODEL);
        ln_kernel<<<gln, blk, 0, stream>>>(X, ln2_s + l * DMODEL, ln2_b + l * DMODEL, Hb, nullptr);
        gemm_k<2><<<g24, blk, 0, stream>>>(Hb, WTl + OW1, b1 + l * DFF, nullptr, MID, BN_TOT, DFF, DMODEL);
        gemm_k<3><<<g6, blk, 0, stream>>>(MID, WTl + OW2, b2 + l * DMODEL, X, X, BN_TOT, DMODEL, DFF);
    }
    ln_kernel<<<gln, blk, 0, stream>>>(X, lnf_s, lnf_b, nullptr, out);
}